// Round 18
// baseline (353.062 us; speedup 1.0000x reference)
//
#include <hip/hip_runtime.h>
#include <math.h>

#define T_TOK 8192
#define D_DIM 2048
#define E_EXP 64
#define CAP   256
#define NCH   256           // T_TOK / 32 chunks
#define TEC   (134217728LL) // T*E*C
#define TE    (T_TOK * E_EXP)
#define KSPLIT 4
#define KLEN   (D_DIM / KSPLIT)

__device__ __forceinline__ int swz(int r) { return (r & 7) ^ ((r >> 3) & 7); }

// ---------------- K1: split-K x4 logits GEMM, BM=64, 4x4 acc/thread (R15 verbatim) ----------------
__global__ __launch_bounds__(256) void k_gemm(const float* __restrict__ x,
                                              const float* __restrict__ wg,
                                              float* __restrict__ part) {
  __shared__ float xs[64 * 64];
  __shared__ float ws[64 * 64];
  const int tid = threadIdx.x;
  const int row0 = (blockIdx.x >> 2) * 64;
  const int kc = blockIdx.x & 3;
  const int kbase = kc * KLEN;
  const int tr = tid & 15;   // output rows tr+16j
  const int tc = tid >> 4;   // output cols tc*4..tc*4+3
  const int sA[4] = {swz(tr), swz(tr + 16), swz(tr + 32), swz(tr + 48)};
  const int sB[4] = {swz(tc * 4 + 0), swz(tc * 4 + 1), swz(tc * 4 + 2), swz(tc * 4 + 3)};
  float acc[4][4] = {{0.f, 0.f, 0.f, 0.f}, {0.f, 0.f, 0.f, 0.f},
                     {0.f, 0.f, 0.f, 0.f}, {0.f, 0.f, 0.f, 0.f}};
  for (int k0 = kbase; k0 < kbase + KLEN; k0 += 64) {
#pragma unroll
    for (int i = 0; i < 4; ++i) {
      const int f = tid + i * 256;
      const int r = f >> 4, g = f & 15;
      const float4 v = *reinterpret_cast<const float4*>(
          &x[(size_t)(row0 + r) * D_DIM + k0 + g * 4]);
      *reinterpret_cast<float4*>(&xs[r * 64 + ((g ^ swz(r)) << 2)]) = v;
    }
#pragma unroll
    for (int i = 0; i < 4; ++i) {
      const int f = tid + i * 256;
      const int r = f >> 4, g = f & 15;
      const float4 v = *reinterpret_cast<const float4*>(
          &wg[(size_t)r * D_DIM + k0 + g * 4]);
      *reinterpret_cast<float4*>(&ws[r * 64 + ((g ^ swz(r)) << 2)]) = v;
    }
    __syncthreads();
#pragma unroll
    for (int g = 0; g < 16; ++g) {
      float4 a[4], b[4];
#pragma unroll
      for (int j = 0; j < 4; ++j) {
        a[j] = *reinterpret_cast<const float4*>(&xs[(tr + 16 * j) * 64 + ((g ^ sA[j]) << 2)]);
        b[j] = *reinterpret_cast<const float4*>(&ws[(tc * 4 + j) * 64 + ((g ^ sB[j]) << 2)]);
      }
#pragma unroll
      for (int jr = 0; jr < 4; ++jr)
#pragma unroll
        for (int jc = 0; jc < 4; ++jc) {
          acc[jr][jc] = fmaf(a[jr].x, b[jc].x, acc[jr][jc]);
          acc[jr][jc] = fmaf(a[jr].y, b[jc].y, acc[jr][jc]);
          acc[jr][jc] = fmaf(a[jr].z, b[jc].z, acc[jr][jc]);
          acc[jr][jc] = fmaf(a[jr].w, b[jc].w, acc[jr][jc]);
        }
    }
    __syncthreads();
  }
  float* pbase = part + (size_t)kc * TE;
#pragma unroll
  for (int jr = 0; jr < 4; ++jr) {
    const float4 o = make_float4(acc[jr][0], acc[jr][1], acc[jr][2], acc[jr][3]);
    *reinterpret_cast<float4*>(&pbase[(size_t)(row0 + tr + 16 * jr) * E_EXP + tc * 4]) = o;
  }
}

// ---------------- K2: fused gate + rank + chunk hist ----------------
// 256 blocks x 256 threads; block b owns tokens [b*32, b*32+32) (wave w: 8
// tokens as A/B ILP pairs). After the gate loop: O(32) in-LDS rank + 64-expert
// chunk histogram. Per-token math bit-identical to R17's gate.
__global__ __launch_bounds__(256) void k_gate(const float* __restrict__ part,
                                              const float* __restrict__ gumbel,
                                              float* __restrict__ colpart,
                                              int* __restrict__ idx1,
                                              int* __restrict__ idx2,
                                              float* __restrict__ g1v,
                                              float* __restrict__ g2v,
                                              int* __restrict__ rank1,
                                              int* __restrict__ rank2,
                                              int* __restrict__ hist1,
                                              int* __restrict__ hist2) {
  __shared__ int sIdx1[32], sIdx2[32];
  __shared__ int h1[64], h2[64];
  __shared__ float cs[4][64];
  const int tid = threadIdx.x;
  const int lane = tid & 63;
  const int wave = tid >> 6;
  const int base = blockIdx.x * 32;
  if (tid < 64) { h1[tid] = 0; h2[tid] = 0; }
  float colacc = 0.f;
  for (int i = 0; i < 4; ++i) {
    const int tA = base + wave * 8 + i;
    const int tB = tA + 4;
    const int oA = tA * 64 + lane;
    const int oB = tB * 64 + lane;
    const float LA = (part[oA] + part[TE + oA]) + (part[2 * TE + oA] + part[3 * TE + oA]);
    const float LB = (part[oB] + part[TE + oB]) + (part[2 * TE + oB] + part[3 * TE + oB]);
    const float gnA = gumbel[oA];
    const float gnB = gumbel[oB];
    // fused max + first-argmax over L (ties -> lowest index)
    float mA = LA; int iA = lane;
    float mB = LB; int iB = lane;
#pragma unroll
    for (int off = 32; off; off >>= 1) {
      const float vA = __shfl_xor(mA, off); const int jA = __shfl_xor(iA, off);
      const float vB = __shfl_xor(mB, off); const int jB = __shfl_xor(iB, off);
      if (vA > mA || (vA == mA && jA < iA)) { mA = vA; iA = jA; }
      if (vB > mB || (vB == mB && jB < iB)) { mB = vB; iB = jB; }
    }
    const float eA = expf(LA - mA);
    const float eB = expf(LB - mB);
    float sA = eA, sB = eB;
#pragma unroll
    for (int off = 32; off; off >>= 1) {
      sA += __shfl_xor(sA, off);
      sB += __shfl_xor(sB, off);
    }
    colacc += eA / sA + eB / sB;
    const float gate1A = 1.0f / sA;   // g[i1] = exp(m-m)/s = 1/s exactly
    const float gate1B = 1.0f / sB;
    // argmax2 over noised logits, expert i1 masked out
    float nA = LA + gnA; if (lane == iA) nA = -INFINITY;
    float nB = LB + gnB; if (lane == iB) nB = -INFINITY;
    float vA2 = nA; int iA2 = lane;
    float vB2 = nB; int iB2 = lane;
#pragma unroll
    for (int off = 32; off; off >>= 1) {
      const float wA = __shfl_xor(vA2, off); const int kA = __shfl_xor(iA2, off);
      const float wB = __shfl_xor(vB2, off); const int kB = __shfl_xor(iB2, off);
      if (wA > vA2 || (wA == vA2 && kA < iA2)) { vA2 = wA; iA2 = kA; }
      if (wB > vB2 || (wB == vB2 && kB < iB2)) { vB2 = wB; iB2 = kB; }
    }
    const float gate2A = __shfl(eA, iA2) / sA;   // = g[i2] (s wave-uniform)
    const float gate2B = __shfl(eB, iB2) / sB;
    if (lane == 0) {
      const int lt = wave * 8 + i;
      sIdx1[lt] = iA; sIdx2[lt] = iA2;
      sIdx1[lt + 4] = iB; sIdx2[lt + 4] = iB2;
      idx1[tA] = iA; idx2[tA] = iA2; g1v[tA] = gate1A; g2v[tA] = gate2A;
      idx1[tB] = iB; idx2[tB] = iB2; g1v[tB] = gate1B; g2v[tB] = gate2B;
    }
  }
  cs[wave][lane] = colacc;
  __syncthreads();
  if (wave == 0) {
    colpart[blockIdx.x * 64 + lane] =
        (cs[0][lane] + cs[1][lane]) + (cs[2][lane] + cs[3][lane]);
  }
  // rank phase: thread t<32 ranks its token within the 32-token chunk
  if (tid < 32) {
    const int my1 = sIdx1[tid], my2 = sIdx2[tid];
    int r1 = 0, r2 = 0;
#pragma unroll
    for (int j = 0; j < 32; ++j) {
      r1 += (j < tid && sIdx1[j] == my1);
      r2 += (j < tid && sIdx2[j] == my2);
    }
    atomicAdd(&h1[my1], 1);
    atomicAdd(&h2[my2], 1);
    rank1[base + tid] = r1;
    rank2[base + tid] = r2;
  }
  __syncthreads();
  if (tid < 64) {
    hist1[blockIdx.x * 64 + tid] = h1[tid];
    hist2[blockIdx.x * 64 + tid] = h2[tid];
  }
}

// ---------------- K3: scatter + per-block prefix + l_aux ----------------
// 32 blocks x 256 threads; block covers 256 tokens = 8 chunks of 32. Threads
// 0-63 recompute the 8 sub-chunk offsets via the fixed-order 256-chunk prefix
// (deterministic); block 0 also computes l_aux. Then all threads scatter.
__global__ __launch_bounds__(256) void k_scatter(const int* __restrict__ idx1,
                                                 const int* __restrict__ idx2,
                                                 const float* __restrict__ g1v,
                                                 const float* __restrict__ g2v,
                                                 const int* __restrict__ rank1,
                                                 const int* __restrict__ rank2,
                                                 const int* __restrict__ hist1,
                                                 const int* __restrict__ hist2,
                                                 const float* __restrict__ colpart,
                                                 float* __restrict__ dout) {
  __shared__ int offs1_s[8][64], offs2_s[8][64];
  const int tid = threadIdx.x;
  const int bid = blockIdx.x;
  if (tid < 64) {
    const int e = tid;
    int run1 = 0;
    for (int c = 0; c < NCH; ++c) {
      if ((c >> 3) == bid) offs1_s[c & 7][e] = run1;
      run1 += hist1[c * 64 + e];
    }
    const int total1 = run1;   // sum(mask1, axis=0)[e]
    int run2 = 0;
    for (int c = 0; c < NCH; ++c) {
      if ((c >> 3) == bid) offs2_s[c & 7][e] = total1 + run2;
      run2 += hist2[c * 64 + e];
    }
    if (bid == 0) {
      float csum = 0.f;
      for (int b = 0; b < 256; ++b) csum += colpart[b * 64 + e];
      const float me = csum / (float)T_TOK;
      const float ce = (float)total1 / (float)T_TOK;
      float val = me * ce;
#pragma unroll
      for (int o = 32; o; o >>= 1) val += __shfl_xor(val, o);
      if (e == 0) dout[0] = val * (float)E_EXP;  // mean(me*ce)*E*E = sum*E
    }
  }
  __syncthreads();
  const int t = bid * 256 + tid;
  const int cc = tid >> 5;   // sub-chunk 0..7
  const int e1 = idx1[t], e2 = idx2[t];
  const int loc1 = offs1_s[cc][e1] + rank1[t];
  const int loc2 = offs2_s[cc][e2] + rank2[t];
  const bool k1 = loc1 < CAP;
  const bool k2 = loc2 < CAP;
  const float a = k1 ? g1v[t] : 0.f;
  const float b = k2 ? g2v[t] : 0.f;
  const float denom = fmaxf(a + b, 1.1920929e-7f);  // FLT_EPSILON
  if (k1) {
    const long long o = 1LL + ((long long)t * 64 + e1) * 256 + loc1;
    dout[o] = a / denom;
    dout[o + TEC] = 1.0f;
  }
  if (k2) {
    const long long o = 1LL + ((long long)t * 64 + e2) * 256 + loc2;
    dout[o] = b / denom;
    dout[o + TEC] = 1.0f;
  }
}

extern "C" void kernel_launch(void* const* d_in, const int* in_sizes, int n_in,
                              void* d_out, int out_size, void* d_ws, size_t ws_size,
                              hipStream_t stream) {
  const float* x = (const float*)d_in[0];
  const float* wg = (const float*)d_in[1];
  const float* gumbel = (const float*)d_in[2];
  float* dout = (float*)d_out;

  // workspace layout (aligned chunks)
  char* p = (char*)d_ws;
  float* part = (float*)p;              p += (size_t)KSPLIT * TE * 4;     // 8 MB
  float* colpart = (float*)p;           p += 256 * 64 * 4;                // 64 KB
  float* g1v = (float*)p;               p += T_TOK * 4;
  float* g2v = (float*)p;               p += T_TOK * 4;
  int* idx1 = (int*)p;                  p += T_TOK * 4;
  int* idx2 = (int*)p;                  p += T_TOK * 4;
  int* rank1 = (int*)p;                 p += T_TOK * 4;
  int* rank2 = (int*)p;                 p += T_TOK * 4;
  int* hist1 = (int*)p;                 p += NCH * 64 * 4;                // 64 KB
  int* hist2 = (int*)p;                 p += NCH * 64 * 4;

  // zero-fill the (sparse) 1.07 GB output — the structural floor of this op
  hipMemsetAsync(d_out, 0, (size_t)out_size * sizeof(float), stream);

  k_gemm<<<(T_TOK / 64) * KSPLIT, 256, 0, stream>>>(x, wg, part);
  k_gate<<<256, 256, 0, stream>>>(part, gumbel, colpart, idx1, idx2, g1v, g2v,
                                  rank1, rank2, hist1, hist2);
  k_scatter<<<NCH / 8, 256, 0, stream>>>(idx1, idx2, g1v, g2v, rank1, rank2,
                                         hist1, hist2, colpart, dout);
}

// Round 19
// 244.011 us; speedup vs baseline: 1.4469x; 1.4469x over previous
//
#include <hip/hip_runtime.h>
#include <math.h>

#define T_TOK 8192
#define D_DIM 2048
#define E_EXP 64
#define CAP   256
#define NCHUNK 32           // T_TOK / 256
#define TEC   (134217728LL) // T*E*C
#define TE    (T_TOK * E_EXP)
#define KSPLIT 4
#define KLEN   (D_DIM / KSPLIT)

__device__ __forceinline__ int swz(int r) { return (r & 7) ^ ((r >> 3) & 7); }

// ---------------- K1: split-K x4 logits GEMM, BM=64, 4x4 acc/thread ----------------
__global__ __launch_bounds__(256) void k_gemm(const float* __restrict__ x,
                                              const float* __restrict__ wg,
                                              float* __restrict__ part) {
  __shared__ float xs[64 * 64];
  __shared__ float ws[64 * 64];
  const int tid = threadIdx.x;
  const int row0 = (blockIdx.x >> 2) * 64;
  const int kc = blockIdx.x & 3;
  const int kbase = kc * KLEN;
  const int tr = tid & 15;   // output rows tr+16j
  const int tc = tid >> 4;   // output cols tc*4..tc*4+3
  const int sA[4] = {swz(tr), swz(tr + 16), swz(tr + 32), swz(tr + 48)};
  const int sB[4] = {swz(tc * 4 + 0), swz(tc * 4 + 1), swz(tc * 4 + 2), swz(tc * 4 + 3)};
  float acc[4][4] = {{0.f, 0.f, 0.f, 0.f}, {0.f, 0.f, 0.f, 0.f},
                     {0.f, 0.f, 0.f, 0.f}, {0.f, 0.f, 0.f, 0.f}};
  for (int k0 = kbase; k0 < kbase + KLEN; k0 += 64) {
#pragma unroll
    for (int i = 0; i < 4; ++i) {
      const int f = tid + i * 256;
      const int r = f >> 4, g = f & 15;
      const float4 v = *reinterpret_cast<const float4*>(
          &x[(size_t)(row0 + r) * D_DIM + k0 + g * 4]);
      *reinterpret_cast<float4*>(&xs[r * 64 + ((g ^ swz(r)) << 2)]) = v;
    }
#pragma unroll
    for (int i = 0; i < 4; ++i) {
      const int f = tid + i * 256;
      const int r = f >> 4, g = f & 15;
      const float4 v = *reinterpret_cast<const float4*>(
          &wg[(size_t)r * D_DIM + k0 + g * 4]);
      *reinterpret_cast<float4*>(&ws[r * 64 + ((g ^ swz(r)) << 2)]) = v;
    }
    __syncthreads();
#pragma unroll
    for (int g = 0; g < 16; ++g) {
      float4 a[4], b[4];
#pragma unroll
      for (int j = 0; j < 4; ++j) {
        a[j] = *reinterpret_cast<const float4*>(&xs[(tr + 16 * j) * 64 + ((g ^ sA[j]) << 2)]);
        b[j] = *reinterpret_cast<const float4*>(&ws[(tc * 4 + j) * 64 + ((g ^ sB[j]) << 2)]);
      }
#pragma unroll
      for (int jr = 0; jr < 4; ++jr)
#pragma unroll
        for (int jc = 0; jc < 4; ++jc) {
          acc[jr][jc] = fmaf(a[jr].x, b[jc].x, acc[jr][jc]);
          acc[jr][jc] = fmaf(a[jr].y, b[jc].y, acc[jr][jc]);
          acc[jr][jc] = fmaf(a[jr].z, b[jc].z, acc[jr][jc]);
          acc[jr][jc] = fmaf(a[jr].w, b[jc].w, acc[jr][jc]);
        }
    }
    __syncthreads();
  }
  float* pbase = part + (size_t)kc * TE;
#pragma unroll
  for (int jr = 0; jr < 4; ++jr) {
    const float4 o = make_float4(acc[jr][0], acc[jr][1], acc[jr][2], acc[jr][3]);
    *reinterpret_cast<float4*>(&pbase[(size_t)(row0 + tr + 16 * jr) * E_EXP + tc * 4]) = o;
  }
}

// ---------------- K2: per-row softmax + top1 + gumbel-top2 ----------------
// fused max+argmax (argmax(softmax)=argmax(L)); gate1 = 1/s (bit-identical);
// 2-token ILP per iteration (A/B chains interleave).
__global__ __launch_bounds__(256) void k_gate(const float* __restrict__ part,
                                              const float* __restrict__ gumbel,
                                              float* __restrict__ colpart,
                                              int* __restrict__ idx1,
                                              int* __restrict__ idx2,
                                              float* __restrict__ g1v,
                                              float* __restrict__ g2v) {
  const int lane = threadIdx.x & 63;
  const int wave = threadIdx.x >> 6;
  const int gwave = blockIdx.x * 4 + wave;  // 0..1023
  float colacc = 0.f;
  for (int i = 0; i < 4; ++i) {
    const int tA = gwave + i * 1024;
    const int tB = tA + 4096;
    const int oA = tA * 64 + lane;
    const int oB = tB * 64 + lane;
    const float LA = (part[oA] + part[TE + oA]) + (part[2 * TE + oA] + part[3 * TE + oA]);
    const float LB = (part[oB] + part[TE + oB]) + (part[2 * TE + oB] + part[3 * TE + oB]);
    const float gnA = gumbel[oA];
    const float gnB = gumbel[oB];
    // fused max + first-argmax over L (ties -> lowest index)
    float mA = LA; int iA = lane;
    float mB = LB; int iB = lane;
#pragma unroll
    for (int off = 32; off; off >>= 1) {
      const float vA = __shfl_xor(mA, off); const int jA = __shfl_xor(iA, off);
      const float vB = __shfl_xor(mB, off); const int jB = __shfl_xor(iB, off);
      if (vA > mA || (vA == mA && jA < iA)) { mA = vA; iA = jA; }
      if (vB > mB || (vB == mB && jB < iB)) { mB = vB; iB = jB; }
    }
    const float eA = expf(LA - mA);
    const float eB = expf(LB - mB);
    float sA = eA, sB = eB;
#pragma unroll
    for (int off = 32; off; off >>= 1) {
      sA += __shfl_xor(sA, off);
      sB += __shfl_xor(sB, off);
    }
    colacc += eA / sA + eB / sB;
    const float gate1A = 1.0f / sA;   // g[i1] = exp(m-m)/s = 1/s exactly
    const float gate1B = 1.0f / sB;
    // argmax2 over noised logits, expert i1 masked out
    float nA = LA + gnA; if (lane == iA) nA = -INFINITY;
    float nB = LB + gnB; if (lane == iB) nB = -INFINITY;
    float vA2 = nA; int iA2 = lane;
    float vB2 = nB; int iB2 = lane;
#pragma unroll
    for (int off = 32; off; off >>= 1) {
      const float wA = __shfl_xor(vA2, off); const int kA = __shfl_xor(iA2, off);
      const float wB = __shfl_xor(vB2, off); const int kB = __shfl_xor(iB2, off);
      if (wA > vA2 || (wA == vA2 && kA < iA2)) { vA2 = wA; iA2 = kA; }
      if (wB > vB2 || (wB == vB2 && kB < iB2)) { vB2 = wB; iB2 = kB; }
    }
    const float gate2A = __shfl(eA, iA2) / sA;   // = g[i2] (s wave-uniform)
    const float gate2B = __shfl(eB, iB2) / sB;
    if (lane == 0) {
      idx1[tA] = iA; idx2[tA] = iA2; g1v[tA] = gate1A; g2v[tA] = gate2A;
      idx1[tB] = iB; idx2[tB] = iB2; g1v[tB] = gate1B; g2v[tB] = gate2B;
    }
  }
  __shared__ float cs[4][64];
  cs[wave][lane] = colacc;
  __syncthreads();
  if (wave == 0) {
    float ssum = cs[0][lane] + cs[1][lane] + cs[2][lane] + cs[3][lane];
    colpart[blockIdx.x * 64 + lane] = ssum;
  }
}

// ---------------- K3: local ranks + chunk histograms ----------------
__global__ __launch_bounds__(256) void k_rank(const int* __restrict__ idx1,
                                              const int* __restrict__ idx2,
                                              int* __restrict__ rank1,
                                              int* __restrict__ rank2,
                                              int* __restrict__ hist1,
                                              int* __restrict__ hist2) {
  __shared__ int s1[256], s2[256];
  __shared__ int h1[64], h2[64];
  const int tid = threadIdx.x;
  const int base = blockIdx.x * 256;
  if (tid < 64) { h1[tid] = 0; h2[tid] = 0; }
  s1[tid] = idx1[base + tid];
  s2[tid] = idx2[base + tid];
  __syncthreads();
  const int my1 = s1[tid], my2 = s2[tid];
  int r1 = 0, r2 = 0;
  for (int j = 0; j < 256; ++j) {
    r1 += (j < tid && s1[j] == my1);
    r2 += (j < tid && s2[j] == my2);
  }
  atomicAdd(&h1[my1], 1);
  atomicAdd(&h2[my2], 1);
  rank1[base + tid] = r1;
  rank2[base + tid] = r2;
  __syncthreads();
  if (tid < 64) {
    hist1[blockIdx.x * 64 + tid] = h1[tid];
    hist2[blockIdx.x * 64 + tid] = h2[tid];
  }
}

// ---------------- K4: scatter + per-block prefix + l_aux ----------------
__global__ __launch_bounds__(256) void k_scatter(const int* __restrict__ idx1,
                                                 const int* __restrict__ idx2,
                                                 const float* __restrict__ g1v,
                                                 const float* __restrict__ g2v,
                                                 const int* __restrict__ rank1,
                                                 const int* __restrict__ rank2,
                                                 const int* __restrict__ hist1,
                                                 const int* __restrict__ hist2,
                                                 const float* __restrict__ colpart,
                                                 float* __restrict__ dout) {
  __shared__ int offs1_s[64], offs2_s[64];
  const int tid = threadIdx.x;
  const int bid = blockIdx.x;
  if (tid < 64) {
    const int e = tid;
    int run1 = 0, pre1 = 0;
    for (int c = 0; c < NCHUNK; ++c) {
      if (c == bid) pre1 = run1;
      run1 += hist1[c * 64 + e];
    }
    const int total1 = run1;   // sum(mask1, axis=0)[e]
    int pre2 = 0;
    for (int c = 0; c < bid; ++c) pre2 += hist2[c * 64 + e];
    offs1_s[e] = pre1;
    offs2_s[e] = total1 + pre2;
    if (bid == 0) {
      float csum = 0.f;
      for (int b = 0; b < 256; ++b) csum += colpart[b * 64 + e];
      const float me = csum / (float)T_TOK;
      const float ce = (float)total1 / (float)T_TOK;
      float val = me * ce;
#pragma unroll
      for (int o = 32; o; o >>= 1) val += __shfl_xor(val, o);
      if (e == 0) dout[0] = val * (float)E_EXP;  // mean(me*ce)*E*E = sum*E
    }
  }
  __syncthreads();
  const int t = bid * 256 + tid;
  const int e1 = idx1[t], e2 = idx2[t];
  const int loc1 = offs1_s[e1] + rank1[t];
  const int loc2 = offs2_s[e2] + rank2[t];
  const bool k1 = loc1 < CAP;
  const bool k2 = loc2 < CAP;
  const float a = k1 ? g1v[t] : 0.f;
  const float b = k2 ? g2v[t] : 0.f;
  const float denom = fmaxf(a + b, 1.1920929e-7f);  // FLT_EPSILON
  if (k1) {
    const long long o = 1LL + ((long long)t * 64 + e1) * 256 + loc1;
    dout[o] = a / denom;
    dout[o + TEC] = 1.0f;
  }
  if (k2) {
    const long long o = 1LL + ((long long)t * 64 + e2) * 256 + loc2;
    dout[o] = b / denom;
    dout[o + TEC] = 1.0f;
  }
}

extern "C" void kernel_launch(void* const* d_in, const int* in_sizes, int n_in,
                              void* d_out, int out_size, void* d_ws, size_t ws_size,
                              hipStream_t stream) {
  const float* x = (const float*)d_in[0];
  const float* wg = (const float*)d_in[1];
  const float* gumbel = (const float*)d_in[2];
  float* dout = (float*)d_out;

  // workspace layout (aligned chunks)
  char* p = (char*)d_ws;
  float* part = (float*)p;              p += (size_t)KSPLIT * TE * 4;     // 8 MB
  float* colpart = (float*)p;           p += 256 * 64 * 4;                // 64 KB
  float* g1v = (float*)p;               p += T_TOK * 4;
  float* g2v = (float*)p;               p += T_TOK * 4;
  int* idx1 = (int*)p;                  p += T_TOK * 4;
  int* idx2 = (int*)p;                  p += T_TOK * 4;
  int* rank1 = (int*)p;                 p += T_TOK * 4;
  int* rank2 = (int*)p;                 p += T_TOK * 4;
  int* hist1 = (int*)p;                 p += NCHUNK * 64 * 4;
  int* hist2 = (int*)p;                 p += NCHUNK * 64 * 4;

  // zero-fill the (sparse) 1.07 GB output — the structural floor of this op
  hipMemsetAsync(d_out, 0, (size_t)out_size * sizeof(float), stream);

  k_gemm<<<(T_TOK / 64) * KSPLIT, 256, 0, stream>>>(x, wg, part);
  k_gate<<<256, 256, 0, stream>>>(part, gumbel, colpart, idx1, idx2, g1v, g2v);
  k_rank<<<NCHUNK, 256, 0, stream>>>(idx1, idx2, rank1, rank2, hist1, hist2);
  k_scatter<<<NCHUNK, 256, 0, stream>>>(idx1, idx2, g1v, g2v, rank1, rank2,
                                        hist1, hist2, colpart, dout);
}